// Round 5
// baseline (260.802 us; speedup 1.0000x reference)
//
#include <hip/hip_runtime.h>

// ---------------------------------------------------------------------------
// LinearAggActor R24 (tier-sorted CSR + merged csr2/proj; coop fusion dead):
//  - math (verified R2-R16): z0 = t2@(w3@w1)+b3@w1 (16-dim); z_k = A^k z0;
//    logits = cvec + sum_k relu(relu(z_k+b1)@w2+b2) @ M_k ; softmax.
//  - R20 post-mortem: -38% gather volume => ZERO delta. Hops are NOT
//    gather-throughput-bound.
//  - R23 post-mortem: timed path (graph capture) was the FALLBACK; coop
//    fused_k only ran under rocprof at 1225us (VALUBusy 1.8%) — persistent
//    fusion is latency-starved at 2 blk/CU and not capturable. ABANDONED.
//  - R24 theory: hop agg wave = 3-epoch dependent chain (lists -> csrp/degs
//    -> gathers). Remove one epoch via TIER-SORTED csr: csr2 places rows
//    directly into csrp_s (3 fixed regions by degree tier) + nd_s{node,deg};
//    hop computes row from idx arithmetically. Also merge csr2+proj into one
//    role-split launch (independent; overlaps VALU proj with latency csr2).
//    10+memset dispatches -> 9+memset.
//  - proj role keeps __launch_bounds__(256) single-arg (R16-R18 3-point:
//    (256)=VGPR256 no-spill fast; (256,4)/none = 104-107MB spill, 2x slow).
//  - build (R10-15): binfill multisplit + setup on idle CUs; sentinel row n.
// ---------------------------------------------------------------------------

#define NB2MAX 400   // bins of 128 dsts: supports n <= 51200
#define NBLK   256   // binfill blocks
#define CAP2   32    // LDS staging per bin
#define CAPC   48    // per-(bin,block) cell capacity (mean 16, +8 sigma)
#define CAPB   6144  // per-bin dense CSR region (overflow tails only)
#define OVCAP  1024  // per-bin overflow region (statistically unused)
#define LCAP   6144  // csr2 per-bin LDS capacity (mean 4096, +32 sigma)
#define CAPN   64    // padded slots per node (mean 32, +5.7 sigma)

// blocks [0,NBLK): multisplit into private (bin,block) cells; packed
// (dloc<<16|src); LDS cursors; no global atomics on the hot path.
// blocks [NBLK, NBLK+9): setup role (R10-verified).
__global__ __launch_bounds__(1024) void binfill_k(
    const int* __restrict__ src, const int* __restrict__ dst, int E, int n,
    int* __restrict__ gcur, int* __restrict__ ovbuf,
    int* __restrict__ bins, int* __restrict__ cnts,
    const float* __restrict__ w1, const float* __restrict__ w3,
    const float* __restrict__ b3, const float* __restrict__ fc1w,
    const float* __restrict__ fc1b, const float* __restrict__ fc2w,
    const float* __restrict__ fc2b,
    float* __restrict__ M, float* __restrict__ cvec,
    float* __restrict__ W31, float* __restrict__ c31) {
    __shared__ int lbuf[NB2MAX * CAP2];
    __shared__ int lcnt[NB2MAX];
    __shared__ int lflush[NB2MAX];
    int tid = threadIdx.x;
    int NB = (n + 127) >> 7;

    if ((int)blockIdx.x >= NBLK) {
        // ---------------- setup role ----------------
        float* fl = (float*)lbuf;   // LDS reuse
        int s = (int)blockIdx.x - NBLK;
        if (s == 0) {
            if (tid < 256) {
                int i = tid >> 4, j = tid & 15;
                float a = 0.f;
                for (int g = 0; g < 64; g++) a += w3[i * 64 + g] * w1[g * 16 + j];
                W31[tid] = a;
            } else if (tid < 272) {
                int j = tid - 256;
                float a = 0.f;
                for (int g = 0; g < 64; g++) a += b3[g] * w1[g * 16 + j];
                c31[j] = a;
            } else if (tid >= 320 && tid < 384) {
                int h = tid - 320;
                float a = 0.f;
                for (int r = 0; r < 512; r++) a += b3[r & 63] * fc1w[r * 64 + h];
                fl[h] = a;   // u[h]
            }
            __syncthreads();
            if (tid < 8) {
                float a = fc2b[tid];
                for (int h = 0; h < 64; h++) a += (fc1b[h] + fl[h]) * fc2w[h * 8 + tid];
                cvec[tid] = a;
            }
        } else {
            int k = s - 1;
            {   // Q_k: one elem per thread
                int i = tid >> 6, h = tid & 63;
                float a = 0.f;
                const float* f1 = fc1w + (size_t)(k * 64) * 64 + h;
                for (int g = 0; g < 64; g++) a += w3[i * 64 + g] * f1[g * 64];
                fl[i * 64 + h] = a;
            }
            __syncthreads();
            if (tid < 128) {
                int i = tid >> 3, j = tid & 7;
                float a = 0.f;
                for (int h = 0; h < 64; h++) a += fl[i * 64 + h] * fc2w[h * 8 + j];
                M[k * 128 + i * 8 + j] = a;
            }
        }
        return;
    }

    // ---------------- binfill role ----------------
    for (int b = tid; b < NB; b += 1024) { lcnt[b] = 0; lflush[b] = 0; }
    __syncthreads();
    int blk = blockIdx.x;
    int chunk = (E + NBLK - 1) / NBLK;
    int beg = blk * chunk;
    int end = beg + chunk; if (end > E) end = E;
    for (int t0 = beg; t0 < end; t0 += 1024) {
        int e = t0 + tid;
        if (e < end) {
            int d = dst[e], s = src[e];
            if ((unsigned)d < (unsigned)n && (unsigned)s < (unsigned)n) {
                int b = d >> 7;
                int pk = ((d & 127) << 16) | s;
                int pos = atomicAdd(&lcnt[b], 1);
                if (pos < CAP2) lbuf[b * CAP2 + pos] = pk;
                else {  // statistically never
                    int p = atomicAdd(&gcur[b], 1);
                    if (p < OVCAP) ovbuf[b * OVCAP + p] = pk;
                }
            }
        }
        __syncthreads();
        for (int b = tid; b < NB; b += 1024) {
            int cnt = lcnt[b]; if (cnt > CAP2) cnt = CAP2;
            int fl2 = lflush[b];
            size_t cell = ((size_t)b * NBLK + blk) * CAPC;
            int base = 0;
            while (cnt - base >= 16) {
                if (fl2 + 16 <= CAPC) {
                    int* dp = bins + cell + fl2;
                    #pragma unroll
                    for (int q = 0; q < 16; q++) dp[q] = lbuf[b * CAP2 + base + q];
                    fl2 += 16;
                } else {  // cell overflow (statistically never)
                    int p = atomicAdd(&gcur[b], 16);
                    for (int q = 0; q < 16; q++)
                        if (p + q < OVCAP) ovbuf[b * OVCAP + p + q] = lbuf[b * CAP2 + base + q];
                }
                base += 16;
            }
            int rem = cnt - base;
            if (base > 0)
                for (int q = 0; q < rem; q++) lbuf[b * CAP2 + q] = lbuf[b * CAP2 + base + q];
            lcnt[b] = rem; lflush[b] = fl2;
        }
        __syncthreads();
    }
    for (int b = tid; b < NB; b += 1024) {
        int cnt = lcnt[b]; if (cnt > CAP2) cnt = CAP2;
        int fl2 = lflush[b];
        size_t cell = ((size_t)b * NBLK + blk) * CAPC;
        if (fl2 + cnt <= CAPC) {
            for (int q = 0; q < cnt; q++) bins[cell + fl2 + q] = lbuf[b * CAP2 + q];
            fl2 += cnt;
        } else {
            int p = atomicAdd(&gcur[b], cnt);
            for (int q = 0; q < cnt; q++)
                if (p + q < OVCAP) ovbuf[b * OVCAP + p + q] = lbuf[b * CAP2 + q];
        }
        cnts[(size_t)blk * NB + b] = fl2;
    }
}

// Merged launch: blocks [0,NB) = csr2 role (counting sort -> TIER-SORTED
// padded ushort csrp_s + nd_s{node,deg}; dense tail csr/be for deg>64);
// blocks [NB,..) = proj role (streamed x -> z0, field0 logits).
// Tier regions: row = idx (t0), n+(idx-ns) (t1), 2n+(idx-ns-nm) (t2).
// csrp permutation: sorted slot j -> pos ((j&3)<<4)|(j>>2): hop slot-group t
// owns 16 contiguous ushorts = two uint4 loads.
__global__ __launch_bounds__(256) void csr2p_k(
    const int* __restrict__ bins, const int* __restrict__ cnts,
    const int* __restrict__ gcur, const int* __restrict__ ovbuf,
    unsigned short* __restrict__ csrp_s, int2* __restrict__ nd_s,
    int* __restrict__ csr, int2* __restrict__ be, int* __restrict__ lcnt3,
    const float* __restrict__ x, float* __restrict__ z0, float* __restrict__ z1,
    float* __restrict__ logits,
    const float* __restrict__ w1, const float* __restrict__ b1,
    const float* __restrict__ w2, const float* __restrict__ b2,
    const float* __restrict__ W31, const float* __restrict__ c31,
    const float* __restrict__ M0, const float* __restrict__ cvec,
    int n, int NBARG) {
    int tid = threadIdx.x;
    if ((int)blockIdx.x < NBARG) {
        // ======================= csr2 role =======================
        __shared__ int hist[128], pref[128], cur[128], slot[128];
        __shared__ int scnt[NBLK];
        __shared__ int lbuf[LCAP];
        __shared__ int sov;
        __shared__ int ccnt[3], cbase[3];
        int NB = (n + 127) >> 7;
        int b = blockIdx.x;
        if (tid < 128) { hist[tid] = 0; cur[tid] = 0; }
        if (tid < 3) ccnt[tid] = 0;
        scnt[tid] = cnts[(size_t)tid * NB + b];
        if (tid == 0) {
            int g = gcur[b];
            sov = g < 0 ? 0 : (g > OVCAP ? OVCAP : g);
        }
        __syncthreads();
        {   // pass 1: histogram of dst-local
            int c = scnt[tid];
            size_t cell = ((size_t)b * NBLK + tid) * CAPC;
            for (int i = 0; i < c; i++) atomicAdd(&hist[bins[cell + i] >> 16], 1);
        }
        if (tid == 0)
            for (int i = 0; i < sov; i++) atomicAdd(&hist[ovbuf[b * OVCAP + i] >> 16], 1);
        __syncthreads();
        if (tid == 0) {
            int r = 0;
            for (int i = 0; i < 128; i++) { pref[i] = r; r += hist[i]; }
        }
        __syncthreads();
        {   // pass 2: place into LDS (bin-locally dense, sorted by dst)
            int c = scnt[tid];
            size_t cell = ((size_t)b * NBLK + tid) * CAPC;
            for (int i = 0; i < c; i++) {
                int pk = bins[cell + i];
                int dl = pk >> 16;
                int pos = pref[dl] + atomicAdd(&cur[dl], 1);
                if (pos < LCAP) lbuf[pos] = pk & 0xffff;
            }
        }
        if (tid == 0) {
            for (int i = 0; i < sov; i++) {
                int pk = ovbuf[b * OVCAP + i];
                int dl = pk >> 16;
                int pos = pref[dl] + atomicAdd(&cur[dl], 1);
                if (pos < LCAP) lbuf[pos] = pk & 0xffff;
            }
        }
        __syncthreads();
        // tier classification -> global sorted slot per node
        int myc = -1, lpos = 0;
        if (tid < 128) {
            int d = (b << 7) + tid;
            if (d < n) {
                int cnt = hist[tid];
                myc = cnt <= 32 ? 0 : (cnt <= 48 ? 1 : 2);
                lpos = atomicAdd(&ccnt[myc], 1);
            }
        }
        __syncthreads();
        if (tid < 3) cbase[tid] = atomicAdd(&lcnt3[tid], ccnt[tid]);
        __syncthreads();
        if (myc >= 0) {
            int d = (b << 7) + tid;
            int cnt = hist[tid];
            int s = myc * n + cbase[myc] + lpos;   // region base myc*n
            slot[tid] = s;
            nd_s[s] = make_int2(d, cnt);
            if (cnt > CAPN) {   // rare tail -> dense region + be (premult x4)
                int s0 = b * CAPB + pref[tid];
                be[d] = make_int2(s0 + CAPN, s0 + cnt);
                for (int j = CAPN; j < cnt; j++)
                    csr[s0 + j] = lbuf[pref[tid] + j] << 2;
            }
        }
        __syncthreads();
        // permuted padded ushort CSR into sorted row; sentinel = n (zero row)
        for (int q = tid; q < 128 * CAPN; q += 256) {
            int dl = q >> 6, j = q & 63;
            int d = (b << 7) + dl;
            if (d >= n) break;
            int cnt = hist[dl];
            int v = (j < cnt) ? lbuf[pref[dl] + j] : n;
            int pos = ((j & 3) << 4) | (j >> 2);
            csrp_s[(size_t)slot[dl] * CAPN + pos] = (unsigned short)v;
        }
        return;
    }
    // ======================= proj role =======================
    __shared__ float sw1[1024], sw2[256], sW[256], sM[128];
    __shared__ float sb1[16], sb2[16], sc[16], scv[8];
    for (int i = tid; i < 1024; i += 256) sw1[i] = w1[i];
    sw2[tid] = w2[tid & 255];
    sW[tid & 255] = W31[tid & 255];
    if (tid < 128) sM[tid] = M0[tid];
    if (tid < 16) { sb1[tid] = b1[tid]; sb2[tid] = b2[tid]; sc[tid] = c31[tid]; }
    if (tid < 8) scv[tid] = cvec[tid];
    __syncthreads();
    if ((int)blockIdx.x == NBARG && tid < 16) {   // zero sentinel row n
        z0[(size_t)n * 16 + tid] = 0.f;
        z1[(size_t)n * 16 + tid] = 0.f;
    }
    int nid = ((int)blockIdx.x - NBARG) * 256 + tid;
    if (nid >= n) return;
    float t1[16];
    #pragma unroll
    for (int j = 0; j < 16; j++) t1[j] = sb1[j];
    const float4* xp = (const float4*)(x + (size_t)nid * 64);
    #pragma unroll
    for (int q = 0; q < 16; q++) {
        float4 v = xp[q];
        #pragma unroll
        for (int j = 0; j < 16; j++)
            t1[j] += v.x * sw1[(4 * q) * 16 + j] + v.y * sw1[(4 * q + 1) * 16 + j]
                   + v.z * sw1[(4 * q + 2) * 16 + j] + v.w * sw1[(4 * q + 3) * 16 + j];
    }
    #pragma unroll
    for (int j = 0; j < 16; j++) t1[j] = fmaxf(t1[j], 0.f);
    float t2[16];
    #pragma unroll
    for (int j = 0; j < 16; j++) {
        float a = sb2[j];
        #pragma unroll
        for (int i = 0; i < 16; i++) a += t1[i] * sw2[i * 16 + j];
        t2[j] = fmaxf(a, 0.f);
    }
    float z[16];
    #pragma unroll
    for (int j = 0; j < 16; j++) {
        float a = sc[j];
        #pragma unroll
        for (int i = 0; i < 16; i++) a += t2[i] * sW[i * 16 + j];
        z[j] = a;
    }
    float4* zo = (float4*)(z0 + (size_t)nid * 16);
    #pragma unroll
    for (int q = 0; q < 4; q++)
        zo[q] = make_float4(z[4 * q], z[4 * q + 1], z[4 * q + 2], z[4 * q + 3]);
    float h[16], f2[16];
    #pragma unroll
    for (int i = 0; i < 16; i++) h[i] = fmaxf(z[i] + sb1[i], 0.f);
    #pragma unroll
    for (int j = 0; j < 16; j++) {
        float a = sb2[j];
        #pragma unroll
        for (int i = 0; i < 16; i++) a += h[i] * sw2[i * 16 + j];
        f2[j] = fmaxf(a, 0.f);
    }
    float* lp = logits + (size_t)nid * 8;
    #pragma unroll
    for (int j = 0; j < 8; j++) {
        float l = scv[j];
        #pragma unroll
        for (int i = 0; i < 16; i++) l += f2[i] * sM[i * 8 + j];
        lp[j] = l;
    }
}

// One launch per hop. Blocks [0,FB): field(z_k) thread-per-node;
// blocks [FB,..): agg, 4 nodes/wave (16 lanes each = 4 slot-groups x 4 chans).
// Tier-sorted: row from idx arithmetic; nd_s + csrp row issue in ONE epoch,
// then gathers (2 dependent epochs total, was 3 via lists indirection).
//   tier0 deg<=32: 1 uint4 -> 8 gathers; tier1 <=48: 2 uint4 -> 12;
//   tier2: full 16 + dense tail for deg>64.
__global__ __launch_bounds__(256, 4) void hop_k(
    const float* __restrict__ zin, float* __restrict__ zout, float* __restrict__ logits,
    const unsigned short* __restrict__ csrp_s, const int2* __restrict__ nd_s,
    const int2* __restrict__ be, const int* __restrict__ csr,
    const int* __restrict__ lcnt3,
    const float* __restrict__ w2, const float* __restrict__ b1,
    const float* __restrict__ b2, const float* __restrict__ M, int n, int FB) {
    __shared__ float sw2[256], sM[128], sb1[16], sb2[16];
    int tid = threadIdx.x;
    if ((int)blockIdx.x < FB) {
        // ---- field role ----
        sw2[tid] = w2[tid];
        if (tid < 128) sM[tid] = M[tid];
        if (tid < 16) { sb1[tid] = b1[tid]; sb2[tid] = b2[tid]; }
        __syncthreads();
        int nid = blockIdx.x * 256 + tid;
        if (nid >= n) return;
        float h[16];
        const float4* zp = (const float4*)(zin + (size_t)nid * 16);
        #pragma unroll
        for (int q = 0; q < 4; q++) {
            float4 v = zp[q];
            h[4 * q] = v.x; h[4 * q + 1] = v.y; h[4 * q + 2] = v.z; h[4 * q + 3] = v.w;
        }
        #pragma unroll
        for (int i = 0; i < 16; i++) h[i] = fmaxf(h[i] + sb1[i], 0.f);
        float t2[16];
        #pragma unroll
        for (int j = 0; j < 16; j++) {
            float a = sb2[j];
            #pragma unroll
            for (int i = 0; i < 16; i++) a += h[i] * sw2[i * 16 + j];
            t2[j] = fmaxf(a, 0.f);
        }
        float* lp = logits + (size_t)nid * 8;
        #pragma unroll
        for (int j = 0; j < 8; j++) {
            float l = 0.f;
            #pragma unroll
            for (int i = 0; i < 16; i++) l += t2[i] * sM[i * 8 + j];
            lp[j] += l;
        }
        return;
    }
    // ---- agg role: 4 nodes per wave, tier-sorted direct rows ----
    int wave = tid >> 6;
    int lane = tid & 63;
    int quarter = lane >> 4;              // which node of the 4
    int l16 = lane & 15;
    int t4 = l16 >> 2, ch = l16 & 3;      // slot-group 0..3, channel 0..3
    int idx = (((int)blockIdx.x - FB) * 4 + wave) * 4 + quarter;
    if (idx >= n) return;
    int ns = lcnt3[0], nm = lcnt3[1];     // uniform scalar loads
    int tier; size_t row;
    if (idx < ns)           { tier = 0; row = (size_t)idx; }
    else if (idx < ns + nm) { tier = 1; row = (size_t)n + (idx - ns); }
    else                    { tier = 2; row = 2 * (size_t)n + (idx - ns - nm); }
    int2 nd = nd_s[row];                  // {node, deg} — same epoch as ip
    int node = nd.x, degi = nd.y;
    const uint4* ip = (const uint4*)(csrp_s + (row << 6));
    uint4 pa = ip[t4 * 2];                // sorted slots j = t4, t4+4, ..., t4+28
    int r0 = pa.x & 0xffff, r1 = pa.x >> 16;
    int r2 = pa.y & 0xffff, r3 = pa.y >> 16;
    int r4 = pa.z & 0xffff, r5 = pa.z >> 16;
    int r6 = pa.w & 0xffff, r7 = pa.w >> 16;
    const float4* z4 = (const float4*)zin;
    float4 v0 = z4[((size_t)r0 << 2) + ch];   // sentinel n -> zero row
    float4 v1 = z4[((size_t)r1 << 2) + ch];
    float4 v2 = z4[((size_t)r2 << 2) + ch];
    float4 v3 = z4[((size_t)r3 << 2) + ch];
    float4 v4 = z4[((size_t)r4 << 2) + ch];
    float4 v5 = z4[((size_t)r5 << 2) + ch];
    float4 v6 = z4[((size_t)r6 << 2) + ch];
    float4 v7 = z4[((size_t)r7 << 2) + ch];
    float ax = ((v0.x + v1.x) + (v2.x + v3.x)) + ((v4.x + v5.x) + (v6.x + v7.x));
    float ay = ((v0.y + v1.y) + (v2.y + v3.y)) + ((v4.y + v5.y) + (v6.y + v7.y));
    float az = ((v0.z + v1.z) + (v2.z + v3.z)) + ((v4.z + v5.z) + (v6.z + v7.z));
    float aw = ((v0.w + v1.w) + (v2.w + v3.w)) + ((v4.w + v5.w) + (v6.w + v7.w));
    if (tier >= 1) {
        uint4 pb = ip[t4 * 2 + 1];        // sorted slots j = t4+32..t4+60
        int r8 = pb.x & 0xffff, r9 = pb.x >> 16;
        int rA = pb.y & 0xffff, rB = pb.y >> 16;
        float4 v8 = z4[((size_t)r8 << 2) + ch];
        float4 v9 = z4[((size_t)r9 << 2) + ch];
        float4 vA = z4[((size_t)rA << 2) + ch];
        float4 vB = z4[((size_t)rB << 2) + ch];
        ax += (v8.x + v9.x) + (vA.x + vB.x);
        ay += (v8.y + v9.y) + (vA.y + vB.y);
        az += (v8.z + v9.z) + (vA.z + vB.z);
        aw += (v8.w + v9.w) + (vA.w + vB.w);
        if (tier == 2) {
            int rC = pb.z & 0xffff, rD = pb.z >> 16;
            int rE = pb.w & 0xffff, rF = pb.w >> 16;
            float4 vC = z4[((size_t)rC << 2) + ch];
            float4 vD = z4[((size_t)rD << 2) + ch];
            float4 vE = z4[((size_t)rE << 2) + ch];
            float4 vF = z4[((size_t)rF << 2) + ch];
            ax += (vC.x + vD.x) + (vE.x + vF.x);
            ay += (vC.y + vD.y) + (vE.y + vF.y);
            az += (vC.z + vD.z) + (vE.z + vF.z);
            aw += (vC.w + vD.w) + (vE.w + vF.w);
            if (degi > CAPN) {            // rare tail via dense csr (4 slots)
                int2 r = be[node];
                for (int q = r.x + t4; q < r.y; q += 4) {
                    float4 v = z4[(size_t)csr[q] + ch];
                    ax += v.x; ay += v.y; az += v.z; aw += v.w;
                }
            }
        }
    }
    // reduce over 4 slot-groups within this 16-lane quarter
    #pragma unroll
    for (int off = 8; off >= 4; off >>= 1) {
        ax += __shfl_down(ax, off, 16);
        ay += __shfl_down(ay, off, 16);
        az += __shfl_down(az, off, 16);
        aw += __shfl_down(aw, off, 16);
    }
    if (l16 < 4) {
        float inv = 1.f / (float)(degi > 0 ? degi : 1);
        ((float4*)(zout + (size_t)node * 16))[l16] =
            make_float4(ax * inv, ay * inv, az * inv, aw * inv);
    }
}

// final: logits += field(z7, M7); softmax; thread-per-node
__global__ __launch_bounds__(256) void fieldsoft_k(
    const float* __restrict__ z, float* __restrict__ logits,
    const float* __restrict__ w2, const float* __restrict__ b1,
    const float* __restrict__ b2, const float* __restrict__ M, int n) {
    __shared__ float sw2[256], sM[128], sb1[16], sb2[16];
    int tid = threadIdx.x;
    sw2[tid] = w2[tid];
    if (tid < 128) sM[tid] = M[tid];
    if (tid < 16) { sb1[tid] = b1[tid]; sb2[tid] = b2[tid]; }
    __syncthreads();
    int nid = blockIdx.x * 256 + tid;
    if (nid >= n) return;
    float h[16];
    const float4* zp = (const float4*)(z + (size_t)nid * 16);
    #pragma unroll
    for (int q = 0; q < 4; q++) {
        float4 v = zp[q];
        h[4 * q] = v.x; h[4 * q + 1] = v.y; h[4 * q + 2] = v.z; h[4 * q + 3] = v.w;
    }
    #pragma unroll
    for (int i = 0; i < 16; i++) h[i] = fmaxf(h[i] + sb1[i], 0.f);
    float t2[16];
    #pragma unroll
    for (int j = 0; j < 16; j++) {
        float a = sb2[j];
        #pragma unroll
        for (int i = 0; i < 16; i++) a += h[i] * sw2[i * 16 + j];
        t2[j] = fmaxf(a, 0.f);
    }
    float4* lp4 = (float4*)(logits + (size_t)nid * 8);
    float4 l0 = lp4[0], l1 = lp4[1];
    float v[8] = {l0.x, l0.y, l0.z, l0.w, l1.x, l1.y, l1.z, l1.w};
    #pragma unroll
    for (int j = 0; j < 8; j++) {
        float l = 0.f;
        #pragma unroll
        for (int i = 0; i < 16; i++) l += t2[i] * sM[i * 8 + j];
        v[j] += l;
    }
    float m = v[0];
    #pragma unroll
    for (int j = 1; j < 8; j++) m = fmaxf(m, v[j]);
    float s = 0.f;
    #pragma unroll
    for (int j = 0; j < 8; j++) { v[j] = expf(v[j] - m); s += v[j]; }
    float inv = 1.f / s;
    lp4[0] = make_float4(v[0] * inv, v[1] * inv, v[2] * inv, v[3] * inv);
    lp4[1] = make_float4(v[4] * inv, v[5] * inv, v[6] * inv, v[7] * inv);
}

extern "C" void kernel_launch(void* const* d_in, const int* in_sizes, int n_in,
                              void* d_out, int out_size, void* d_ws, size_t ws_size,
                              hipStream_t stream) {
    const float* x    = (const float*)d_in[0];
    const int*   ei   = (const int*)d_in[1];
    const float* w1   = (const float*)d_in[2];
    const float* b1   = (const float*)d_in[3];
    const float* w2   = (const float*)d_in[4];
    const float* b2   = (const float*)d_in[5];
    const float* w3   = (const float*)d_in[6];
    const float* b3   = (const float*)d_in[7];
    const float* fc1w = (const float*)d_in[8];
    const float* fc1b = (const float*)d_in[9];
    const float* fc2w = (const float*)d_in[10];
    const float* fc2b = (const float*)d_in[11];
    float* out = (float*)d_out;

    int n = in_sizes[0] / 64;
    int E = in_sizes[1] / 2;
    int NB = (n + 127) >> 7;   // 391 for n=50000; NB <= NB2MAX
    const int* src = ei;
    const int* dst = ei + E;

    char* ws = (char*)d_ws;
    auto carve = [&](size_t bytes) {
        char* p = ws;
        ws += (bytes + 255) & ~((size_t)255);
        return p;
    };
    int*   gcur    = (int*)carve((size_t)NB * 4);
    int*   lcnt3   = (int*)carve(16);                 // contiguous after gcur pad
    int*   ovbuf   = (int*)carve((size_t)NB * OVCAP * 4);
    int*   binsbuf = (int*)carve((size_t)NB * NBLK * CAPC * 4);
    int*   cnts    = (int*)carve((size_t)NBLK * NB * 4);
    unsigned short* csrp_s = (unsigned short*)carve((size_t)3 * n * CAPN * 2); // tier-sorted
    int2*  nd_s    = (int2*)carve((size_t)3 * n * 8);                          // {node,deg}
    int*   csr     = (int*)carve((size_t)NB * CAPB * 4);
    int2*  be      = (int2*)carve((size_t)n * 8);
    float* buf0    = (float*)carve((size_t)(n + 1) * 16 * 4);  // +1 zero row
    float* buf1    = (float*)carve((size_t)(n + 1) * 16 * 4);
    float* M       = (float*)carve(1024 * 4);
    float* cvec    = (float*)carve(8 * 4);
    float* W31     = (float*)carve(256 * 4);
    float* c31     = (float*)carve(16 * 4);

    // one memset covers gcur (padded to 256) + lcnt3 (next carve slot)
    size_t gpad = ((size_t)NB * 4 + 255) & ~((size_t)255);
    hipMemsetAsync(gcur, 0, gpad + 16, stream);
    binfill_k<<<NBLK + 9, 1024, 0, stream>>>(src, dst, E, n, gcur, ovbuf, binsbuf, cnts,
                                             w1, w3, b3, fc1w, fc1b, fc2w, fc2b,
                                             M, cvec, W31, c31);

    int FB = (n + 255) / 256;     // field/proj blocks
    int AB = (n + 15) / 16;       // agg blocks (4 nodes/wave, 4 waves/block)
    // merged csr2 + proj launch (independent roles)
    csr2p_k<<<NB + FB, 256, 0, stream>>>(binsbuf, cnts, gcur, ovbuf,
                                         csrp_s, nd_s, csr, be, lcnt3,
                                         x, buf0, buf1, out, w1, b1, w2, b2,
                                         W31, c31, M, cvec, n, NB);

    float* cur = buf0;
    float* nxt = buf1;
    // hop 1: agg only (field0 applied in proj)
    hop_k<<<AB, 256, 0, stream>>>(cur, nxt, out, csrp_s, nd_s, be, csr, lcnt3,
                                  w2, b1, b2, M, n, 0);
    { float* t = cur; cur = nxt; nxt = t; }
    // hops 2..7: field(z_k, M_k) + agg(z_k -> z_{k+1}) in one launch
    for (int k = 1; k <= 6; k++) {
        hop_k<<<FB + AB, 256, 0, stream>>>(cur, nxt, out, csrp_s, nd_s, be, csr,
                                           lcnt3, w2, b1, b2, M + k * 128, n, FB);
        float* t = cur; cur = nxt; nxt = t;
    }
    // final: field(z7, M7) + softmax
    fieldsoft_k<<<FB, 256, 0, stream>>>(cur, out, w2, b1, b2, M + 7 * 128, n);
}

// Round 6
// 240.161 us; speedup vs baseline: 1.0859x; 1.0859x over previous
//
#include <hip/hip_runtime.h>
#include <hip/hip_fp16.h>

// ---------------------------------------------------------------------------
// LinearAggActor R25 (split csr2/proj + FP16 z gathers):
//  - math (verified R2-R16): z0 = t2@(w3@w1)+b3@w1 (16-dim); z_k = A^k z0;
//    logits = cvec + sum_k relu(relu(z_k+b1)@w2+b2) @ M_k ; softmax.
//  - R24 post-mortem: csr2p merge = VGPR contamination (proj's 256 VGPR
//    capped csr2 at 2 blk/CU, 51.6us, occ 8%). SPLIT BACK. Tier-sorted
//    csrp_s/nd_s kept (2-epoch hop chain).
//  - R20 re-read: the 38%-cut slots were SENTINEL reads = one hot cacheline
//    (L1 broadcast, free). Real gather traffic = E x 64B ~ 102MB/hop of
//    random cross-XCD lines at L3 BW ~ 18-22us/hop. Theory NOT falsified.
//  - R25: z stored FP16 (rows = 16 halfs = 32B). Gathers become uint2
//    (4 halfs/lane, 4 lanes coalesce one 32B row) -> hop gather bytes HALVE.
//    fp32 accumulate; ~5e-4 rel rounding/hop, predicted absmax <= 2.5e-3
//    (threshold 2.695e-3, currently 9.8e-4).
//  - proj keeps __launch_bounds__(256) single-arg (R16-R18 3-point: (256) =
//    VGPR 256 no-spill; (256,4)/none = 104-107MB spill, 2x slow).
//  - build (R10-15): binfill multisplit + setup on idle CUs; sentinel row n.
// ---------------------------------------------------------------------------

#define NB2MAX 400   // bins of 128 dsts: supports n <= 51200
#define NBLK   256   // binfill blocks
#define CAP2   32    // LDS staging per bin
#define CAPC   48    // per-(bin,block) cell capacity (mean 16, +8 sigma)
#define CAPB   6144  // per-bin dense CSR region (overflow tails only)
#define OVCAP  1024  // per-bin overflow region (statistically unused)
#define LCAP   6144  // csr2 per-bin LDS capacity (mean 4096, +32 sigma)
#define CAPN   64    // padded slots per node (mean 32, +5.7 sigma)

// blocks [0,NBLK): multisplit into private (bin,block) cells; packed
// (dloc<<16|src); LDS cursors; no global atomics on the hot path.
// blocks [NBLK, NBLK+9): setup role (R10-verified).
__global__ __launch_bounds__(1024) void binfill_k(
    const int* __restrict__ src, const int* __restrict__ dst, int E, int n,
    int* __restrict__ gcur, int* __restrict__ ovbuf,
    int* __restrict__ bins, int* __restrict__ cnts,
    const float* __restrict__ w1, const float* __restrict__ w3,
    const float* __restrict__ b3, const float* __restrict__ fc1w,
    const float* __restrict__ fc1b, const float* __restrict__ fc2w,
    const float* __restrict__ fc2b,
    float* __restrict__ M, float* __restrict__ cvec,
    float* __restrict__ W31, float* __restrict__ c31) {
    __shared__ int lbuf[NB2MAX * CAP2];
    __shared__ int lcnt[NB2MAX];
    __shared__ int lflush[NB2MAX];
    int tid = threadIdx.x;
    int NB = (n + 127) >> 7;

    if ((int)blockIdx.x >= NBLK) {
        // ---------------- setup role ----------------
        float* fl = (float*)lbuf;   // LDS reuse
        int s = (int)blockIdx.x - NBLK;
        if (s == 0) {
            if (tid < 256) {
                int i = tid >> 4, j = tid & 15;
                float a = 0.f;
                for (int g = 0; g < 64; g++) a += w3[i * 64 + g] * w1[g * 16 + j];
                W31[tid] = a;
            } else if (tid < 272) {
                int j = tid - 256;
                float a = 0.f;
                for (int g = 0; g < 64; g++) a += b3[g] * w1[g * 16 + j];
                c31[j] = a;
            } else if (tid >= 320 && tid < 384) {
                int h = tid - 320;
                float a = 0.f;
                for (int r = 0; r < 512; r++) a += b3[r & 63] * fc1w[r * 64 + h];
                fl[h] = a;   // u[h]
            }
            __syncthreads();
            if (tid < 8) {
                float a = fc2b[tid];
                for (int h = 0; h < 64; h++) a += (fc1b[h] + fl[h]) * fc2w[h * 8 + tid];
                cvec[tid] = a;
            }
        } else {
            int k = s - 1;
            {   // Q_k: one elem per thread
                int i = tid >> 6, h = tid & 63;
                float a = 0.f;
                const float* f1 = fc1w + (size_t)(k * 64) * 64 + h;
                for (int g = 0; g < 64; g++) a += w3[i * 64 + g] * f1[g * 64];
                fl[i * 64 + h] = a;
            }
            __syncthreads();
            if (tid < 128) {
                int i = tid >> 3, j = tid & 7;
                float a = 0.f;
                for (int h = 0; h < 64; h++) a += fl[i * 64 + h] * fc2w[h * 8 + j];
                M[k * 128 + i * 8 + j] = a;
            }
        }
        return;
    }

    // ---------------- binfill role ----------------
    for (int b = tid; b < NB; b += 1024) { lcnt[b] = 0; lflush[b] = 0; }
    __syncthreads();
    int blk = blockIdx.x;
    int chunk = (E + NBLK - 1) / NBLK;
    int beg = blk * chunk;
    int end = beg + chunk; if (end > E) end = E;
    for (int t0 = beg; t0 < end; t0 += 1024) {
        int e = t0 + tid;
        if (e < end) {
            int d = dst[e], s = src[e];
            if ((unsigned)d < (unsigned)n && (unsigned)s < (unsigned)n) {
                int b = d >> 7;
                int pk = ((d & 127) << 16) | s;
                int pos = atomicAdd(&lcnt[b], 1);
                if (pos < CAP2) lbuf[b * CAP2 + pos] = pk;
                else {  // statistically never
                    int p = atomicAdd(&gcur[b], 1);
                    if (p < OVCAP) ovbuf[b * OVCAP + p] = pk;
                }
            }
        }
        __syncthreads();
        for (int b = tid; b < NB; b += 1024) {
            int cnt = lcnt[b]; if (cnt > CAP2) cnt = CAP2;
            int fl2 = lflush[b];
            size_t cell = ((size_t)b * NBLK + blk) * CAPC;
            int base = 0;
            while (cnt - base >= 16) {
                if (fl2 + 16 <= CAPC) {
                    int* dp = bins + cell + fl2;
                    #pragma unroll
                    for (int q = 0; q < 16; q++) dp[q] = lbuf[b * CAP2 + base + q];
                    fl2 += 16;
                } else {  // cell overflow (statistically never)
                    int p = atomicAdd(&gcur[b], 16);
                    for (int q = 0; q < 16; q++)
                        if (p + q < OVCAP) ovbuf[b * OVCAP + p + q] = lbuf[b * CAP2 + base + q];
                }
                base += 16;
            }
            int rem = cnt - base;
            if (base > 0)
                for (int q = 0; q < rem; q++) lbuf[b * CAP2 + q] = lbuf[b * CAP2 + base + q];
            lcnt[b] = rem; lflush[b] = fl2;
        }
        __syncthreads();
    }
    for (int b = tid; b < NB; b += 1024) {
        int cnt = lcnt[b]; if (cnt > CAP2) cnt = CAP2;
        int fl2 = lflush[b];
        size_t cell = ((size_t)b * NBLK + blk) * CAPC;
        if (fl2 + cnt <= CAPC) {
            for (int q = 0; q < cnt; q++) bins[cell + fl2 + q] = lbuf[b * CAP2 + q];
            fl2 += cnt;
        } else {
            int p = atomicAdd(&gcur[b], cnt);
            for (int q = 0; q < cnt; q++)
                if (p + q < OVCAP) ovbuf[b * OVCAP + p + q] = lbuf[b * CAP2 + q];
        }
        cnts[(size_t)blk * NB + b] = fl2;
    }
}

// per-bin counting sort -> TIER-SORTED permuted padded ushort csrp_s +
// nd_s{node,deg} (+ dense tail csr/be for deg>64). One WG per bin; int-only,
// LOW VGPR (standalone: no proj contamination — R24 lesson).
// Tier regions: row = idx (t0), n+(idx-ns) (t1), 2n+(idx-ns-nm) (t2).
// csrp permutation: sorted slot j -> pos ((j&3)<<4)|(j>>2).
__global__ __launch_bounds__(256) void csr2_k(
    const int* __restrict__ bins, const int* __restrict__ cnts,
    const int* __restrict__ gcur, const int* __restrict__ ovbuf,
    unsigned short* __restrict__ csrp_s, int2* __restrict__ nd_s,
    int* __restrict__ csr, int2* __restrict__ be, int* __restrict__ lcnt3,
    int n) {
    __shared__ int hist[128], pref[128], cur[128], slot[128];
    __shared__ int scnt[NBLK];
    __shared__ int lbuf[LCAP];
    __shared__ int sov;
    __shared__ int ccnt[3], cbase[3];
    int tid = threadIdx.x;
    int NB = (n + 127) >> 7;
    int b = blockIdx.x;
    if (tid < 128) { hist[tid] = 0; cur[tid] = 0; }
    if (tid < 3) ccnt[tid] = 0;
    scnt[tid] = cnts[(size_t)tid * NB + b];
    if (tid == 0) {
        int g = gcur[b];
        sov = g < 0 ? 0 : (g > OVCAP ? OVCAP : g);
    }
    __syncthreads();
    {   // pass 1: histogram of dst-local
        int c = scnt[tid];
        size_t cell = ((size_t)b * NBLK + tid) * CAPC;
        for (int i = 0; i < c; i++) atomicAdd(&hist[bins[cell + i] >> 16], 1);
    }
    if (tid == 0)
        for (int i = 0; i < sov; i++) atomicAdd(&hist[ovbuf[b * OVCAP + i] >> 16], 1);
    __syncthreads();
    if (tid == 0) {
        int r = 0;
        for (int i = 0; i < 128; i++) { pref[i] = r; r += hist[i]; }
    }
    __syncthreads();
    {   // pass 2: place into LDS (bin-locally dense, sorted by dst)
        int c = scnt[tid];
        size_t cell = ((size_t)b * NBLK + tid) * CAPC;
        for (int i = 0; i < c; i++) {
            int pk = bins[cell + i];
            int dl = pk >> 16;
            int pos = pref[dl] + atomicAdd(&cur[dl], 1);
            if (pos < LCAP) lbuf[pos] = pk & 0xffff;
        }
    }
    if (tid == 0) {
        for (int i = 0; i < sov; i++) {
            int pk = ovbuf[b * OVCAP + i];
            int dl = pk >> 16;
            int pos = pref[dl] + atomicAdd(&cur[dl], 1);
            if (pos < LCAP) lbuf[pos] = pk & 0xffff;
        }
    }
    __syncthreads();
    // tier classification -> global sorted slot per node
    int myc = -1, lpos = 0;
    if (tid < 128) {
        int d = (b << 7) + tid;
        if (d < n) {
            int cnt = hist[tid];
            myc = cnt <= 32 ? 0 : (cnt <= 48 ? 1 : 2);
            lpos = atomicAdd(&ccnt[myc], 1);
        }
    }
    __syncthreads();
    if (tid < 3) cbase[tid] = atomicAdd(&lcnt3[tid], ccnt[tid]);
    __syncthreads();
    if (myc >= 0) {
        int d = (b << 7) + tid;
        int cnt = hist[tid];
        int s = myc * n + cbase[myc] + lpos;   // region base myc*n
        slot[tid] = s;
        nd_s[s] = make_int2(d, cnt);
        if (cnt > CAPN) {   // rare tail -> dense region + be (premult x4)
            int s0 = b * CAPB + pref[tid];
            be[d] = make_int2(s0 + CAPN, s0 + cnt);
            for (int j = CAPN; j < cnt; j++)
                csr[s0 + j] = lbuf[pref[tid] + j] << 2;
        }
    }
    __syncthreads();
    // permuted padded ushort CSR into sorted row; sentinel = n (zero row)
    for (int q = tid; q < 128 * CAPN; q += 256) {
        int dl = q >> 6, j = q & 63;
        int d = (b << 7) + dl;
        if (d >= n) break;
        int cnt = hist[dl];
        int v = (j < cnt) ? lbuf[pref[dl] + j] : n;
        int pos = ((j & 3) << 4) | (j >> 2);
        csrp_s[(size_t)slot[dl] * CAPN + pos] = (unsigned short)v;
    }
}

// unpack one uint2 (4 halfs = one channel quad) and accumulate
__device__ __forceinline__ void acc_row(uint2 u, float& ax, float& ay,
                                        float& az, float& aw) {
    __half2 p = *reinterpret_cast<const __half2*>(&u.x);
    __half2 q = *reinterpret_cast<const __half2*>(&u.y);
    float2 f = __half22float2(p), g = __half22float2(q);
    ax += f.x; ay += f.y; az += g.x; aw += g.y;
}

// proj (streamed x -> z0 FP16) + field0 (logits = cvec + f0); zero sentinels.
// __launch_bounds__(256) single-arg REQUIRED (R16-R18 3-point measured).
__global__ __launch_bounds__(256) void proj_k(
    const float* __restrict__ x, __half* __restrict__ z0, __half* __restrict__ z1,
    float* __restrict__ logits,
    const float* __restrict__ w1, const float* __restrict__ b1,
    const float* __restrict__ w2, const float* __restrict__ b2,
    const float* __restrict__ W31, const float* __restrict__ c31,
    const float* __restrict__ M0, const float* __restrict__ cvec, int n) {
    __shared__ float sw1[1024], sw2[256], sW[256], sM[128];
    __shared__ float sb1[16], sb2[16], sc[16], scv[8];
    int tid = threadIdx.x;
    for (int i = tid; i < 1024; i += 256) sw1[i] = w1[i];
    sw2[tid] = w2[tid & 255];
    sW[tid & 255] = W31[tid & 255];
    if (tid < 128) sM[tid] = M0[tid];
    if (tid < 16) { sb1[tid] = b1[tid]; sb2[tid] = b2[tid]; sc[tid] = c31[tid]; }
    if (tid < 8) scv[tid] = cvec[tid];
    __syncthreads();
    if (blockIdx.x == 0 && tid < 16) {   // zero sentinel row n of both bufs
        ((unsigned short*)z0)[(size_t)n * 16 + tid] = 0;
        ((unsigned short*)z1)[(size_t)n * 16 + tid] = 0;
    }
    int nid = blockIdx.x * 256 + tid;
    if (nid >= n) return;
    float t1[16];
    #pragma unroll
    for (int j = 0; j < 16; j++) t1[j] = sb1[j];
    const float4* xp = (const float4*)(x + (size_t)nid * 64);
    #pragma unroll
    for (int q = 0; q < 16; q++) {
        float4 v = xp[q];
        #pragma unroll
        for (int j = 0; j < 16; j++)
            t1[j] += v.x * sw1[(4 * q) * 16 + j] + v.y * sw1[(4 * q + 1) * 16 + j]
                   + v.z * sw1[(4 * q + 2) * 16 + j] + v.w * sw1[(4 * q + 3) * 16 + j];
    }
    #pragma unroll
    for (int j = 0; j < 16; j++) t1[j] = fmaxf(t1[j], 0.f);
    float t2[16];
    #pragma unroll
    for (int j = 0; j < 16; j++) {
        float a = sb2[j];
        #pragma unroll
        for (int i = 0; i < 16; i++) a += t1[i] * sw2[i * 16 + j];
        t2[j] = fmaxf(a, 0.f);
    }
    float z[16];
    #pragma unroll
    for (int j = 0; j < 16; j++) {
        float a = sc[j];
        #pragma unroll
        for (int i = 0; i < 16; i++) a += t2[i] * sW[i * 16 + j];
        z[j] = a;
    }
    __half2* zo = (__half2*)(z0 + (size_t)nid * 16);
    #pragma unroll
    for (int q = 0; q < 8; q++)
        zo[q] = __floats2half2_rn(z[2 * q], z[2 * q + 1]);
    float h[16], f2[16];
    #pragma unroll
    for (int i = 0; i < 16; i++) h[i] = fmaxf(z[i] + sb1[i], 0.f);
    #pragma unroll
    for (int j = 0; j < 16; j++) {
        float a = sb2[j];
        #pragma unroll
        for (int i = 0; i < 16; i++) a += h[i] * sw2[i * 16 + j];
        f2[j] = fmaxf(a, 0.f);
    }
    float* lp = logits + (size_t)nid * 8;
    #pragma unroll
    for (int j = 0; j < 8; j++) {
        float l = scv[j];
        #pragma unroll
        for (int i = 0; i < 16; i++) l += f2[i] * sM[i * 8 + j];
        lp[j] = l;
    }
}

// One launch per hop. Blocks [0,FB): field(z_k) thread-per-node;
// blocks [FB,..): agg, 4 nodes/wave (16 lanes = 4 slot-groups x 4 chan-quads).
// z rows = 16 halfs = 32B; lane reads uint2 (4 halfs); 4 chan lanes coalesce
// one row. Tier-sorted rows (2-epoch chain): tier0 8 gathers, tier1 12,
// tier2 16 + dense tail.
__global__ __launch_bounds__(256, 4) void hop_k(
    const __half* __restrict__ zin, __half* __restrict__ zout,
    float* __restrict__ logits,
    const unsigned short* __restrict__ csrp_s, const int2* __restrict__ nd_s,
    const int2* __restrict__ be, const int* __restrict__ csr,
    const int* __restrict__ lcnt3,
    const float* __restrict__ w2, const float* __restrict__ b1,
    const float* __restrict__ b2, const float* __restrict__ M, int n, int FB) {
    __shared__ float sw2[256], sM[128], sb1[16], sb2[16];
    int tid = threadIdx.x;
    if ((int)blockIdx.x < FB) {
        // ---- field role ----
        sw2[tid] = w2[tid];
        if (tid < 128) sM[tid] = M[tid];
        if (tid < 16) { sb1[tid] = b1[tid]; sb2[tid] = b2[tid]; }
        __syncthreads();
        int nid = blockIdx.x * 256 + tid;
        if (nid >= n) return;
        float h[16];
        const __half2* zp = (const __half2*)(zin + (size_t)nid * 16);
        #pragma unroll
        for (int q = 0; q < 8; q++) {
            float2 f = __half22float2(zp[q]);
            h[2 * q] = f.x; h[2 * q + 1] = f.y;
        }
        #pragma unroll
        for (int i = 0; i < 16; i++) h[i] = fmaxf(h[i] + sb1[i], 0.f);
        float t2[16];
        #pragma unroll
        for (int j = 0; j < 16; j++) {
            float a = sb2[j];
            #pragma unroll
            for (int i = 0; i < 16; i++) a += h[i] * sw2[i * 16 + j];
            t2[j] = fmaxf(a, 0.f);
        }
        float* lp = logits + (size_t)nid * 8;
        #pragma unroll
        for (int j = 0; j < 8; j++) {
            float l = 0.f;
            #pragma unroll
            for (int i = 0; i < 16; i++) l += t2[i] * sM[i * 8 + j];
            lp[j] += l;
        }
        return;
    }
    // ---- agg role: 4 nodes per wave, tier-sorted direct rows ----
    int wave = tid >> 6;
    int lane = tid & 63;
    int quarter = lane >> 4;              // which node of the 4
    int l16 = lane & 15;
    int t4 = l16 >> 2, ch = l16 & 3;      // slot-group 0..3, chan-quad 0..3
    int idx = (((int)blockIdx.x - FB) * 4 + wave) * 4 + quarter;
    if (idx >= n) return;
    int ns = lcnt3[0], nm = lcnt3[1];     // uniform scalar loads
    int tier; size_t row;
    if (idx < ns)           { tier = 0; row = (size_t)idx; }
    else if (idx < ns + nm) { tier = 1; row = (size_t)n + (idx - ns); }
    else                    { tier = 2; row = 2 * (size_t)n + (idx - ns - nm); }
    int2 nd = nd_s[row];                  // {node, deg} — same epoch as ip
    int node = nd.x, degi = nd.y;
    const uint4* ip = (const uint4*)(csrp_s + (row << 6));
    uint4 pa = ip[t4 * 2];                // sorted slots j = t4, t4+4, ..., t4+28
    int r0 = pa.x & 0xffff, r1 = pa.x >> 16;
    int r2 = pa.y & 0xffff, r3 = pa.y >> 16;
    int r4 = pa.z & 0xffff, r5 = pa.z >> 16;
    int r6 = pa.w & 0xffff, r7 = pa.w >> 16;
    const uint2* z2 = (const uint2*)zin;  // row stride = 4 uint2 (32B)
    uint2 u0 = z2[((size_t)r0 << 2) + ch];   // sentinel n -> zero row
    uint2 u1 = z2[((size_t)r1 << 2) + ch];
    uint2 u2 = z2[((size_t)r2 << 2) + ch];
    uint2 u3 = z2[((size_t)r3 << 2) + ch];
    uint2 u4 = z2[((size_t)r4 << 2) + ch];
    uint2 u5 = z2[((size_t)r5 << 2) + ch];
    uint2 u6 = z2[((size_t)r6 << 2) + ch];
    uint2 u7 = z2[((size_t)r7 << 2) + ch];
    float ax = 0.f, ay = 0.f, az = 0.f, aw = 0.f;
    acc_row(u0, ax, ay, az, aw); acc_row(u1, ax, ay, az, aw);
    acc_row(u2, ax, ay, az, aw); acc_row(u3, ax, ay, az, aw);
    acc_row(u4, ax, ay, az, aw); acc_row(u5, ax, ay, az, aw);
    acc_row(u6, ax, ay, az, aw); acc_row(u7, ax, ay, az, aw);
    if (tier >= 1) {
        uint4 pb = ip[t4 * 2 + 1];        // sorted slots j = t4+32..t4+60
        int r8 = pb.x & 0xffff, r9 = pb.x >> 16;
        int rA = pb.y & 0xffff, rB = pb.y >> 16;
        uint2 u8 = z2[((size_t)r8 << 2) + ch];
        uint2 u9 = z2[((size_t)r9 << 2) + ch];
        uint2 uA = z2[((size_t)rA << 2) + ch];
        uint2 uB = z2[((size_t)rB << 2) + ch];
        acc_row(u8, ax, ay, az, aw); acc_row(u9, ax, ay, az, aw);
        acc_row(uA, ax, ay, az, aw); acc_row(uB, ax, ay, az, aw);
        if (tier == 2) {
            int rC = pb.z & 0xffff, rD = pb.z >> 16;
            int rE = pb.w & 0xffff, rF = pb.w >> 16;
            uint2 uC = z2[((size_t)rC << 2) + ch];
            uint2 uD = z2[((size_t)rD << 2) + ch];
            uint2 uE = z2[((size_t)rE << 2) + ch];
            uint2 uF = z2[((size_t)rF << 2) + ch];
            acc_row(uC, ax, ay, az, aw); acc_row(uD, ax, ay, az, aw);
            acc_row(uE, ax, ay, az, aw); acc_row(uF, ax, ay, az, aw);
            if (degi > CAPN) {            // rare tail via dense csr (4 slots)
                int2 r = be[node];
                for (int q = r.x + t4; q < r.y; q += 4) {
                    uint2 u = z2[(size_t)csr[q] + ch];   // csr premult x4
                    acc_row(u, ax, ay, az, aw);
                }
            }
        }
    }
    // reduce over 4 slot-groups within this 16-lane quarter
    #pragma unroll
    for (int off = 8; off >= 4; off >>= 1) {
        ax += __shfl_down(ax, off, 16);
        ay += __shfl_down(ay, off, 16);
        az += __shfl_down(az, off, 16);
        aw += __shfl_down(aw, off, 16);
    }
    if (l16 < 4) {
        float inv = 1.f / (float)(degi > 0 ? degi : 1);
        __half2 h01 = __floats2half2_rn(ax * inv, ay * inv);
        __half2 h23 = __floats2half2_rn(az * inv, aw * inv);
        uint2 w;
        w.x = *reinterpret_cast<unsigned int*>(&h01);
        w.y = *reinterpret_cast<unsigned int*>(&h23);
        ((uint2*)(zout + (size_t)node * 16))[l16] = w;
    }
}

// final: logits += field(z7, M7); softmax; thread-per-node
__global__ __launch_bounds__(256) void fieldsoft_k(
    const __half* __restrict__ z, float* __restrict__ logits,
    const float* __restrict__ w2, const float* __restrict__ b1,
    const float* __restrict__ b2, const float* __restrict__ M, int n) {
    __shared__ float sw2[256], sM[128], sb1[16], sb2[16];
    int tid = threadIdx.x;
    sw2[tid] = w2[tid];
    if (tid < 128) sM[tid] = M[tid];
    if (tid < 16) { sb1[tid] = b1[tid]; sb2[tid] = b2[tid]; }
    __syncthreads();
    int nid = blockIdx.x * 256 + tid;
    if (nid >= n) return;
    float h[16];
    const __half2* zp = (const __half2*)(z + (size_t)nid * 16);
    #pragma unroll
    for (int q = 0; q < 8; q++) {
        float2 f = __half22float2(zp[q]);
        h[2 * q] = f.x; h[2 * q + 1] = f.y;
    }
    #pragma unroll
    for (int i = 0; i < 16; i++) h[i] = fmaxf(h[i] + sb1[i], 0.f);
    float t2[16];
    #pragma unroll
    for (int j = 0; j < 16; j++) {
        float a = sb2[j];
        #pragma unroll
        for (int i = 0; i < 16; i++) a += h[i] * sw2[i * 16 + j];
        t2[j] = fmaxf(a, 0.f);
    }
    float4* lp4 = (float4*)(logits + (size_t)nid * 8);
    float4 l0 = lp4[0], l1 = lp4[1];
    float v[8] = {l0.x, l0.y, l0.z, l0.w, l1.x, l1.y, l1.z, l1.w};
    #pragma unroll
    for (int j = 0; j < 8; j++) {
        float l = 0.f;
        #pragma unroll
        for (int i = 0; i < 16; i++) l += t2[i] * sM[i * 8 + j];
        v[j] += l;
    }
    float m = v[0];
    #pragma unroll
    for (int j = 1; j < 8; j++) m = fmaxf(m, v[j]);
    float s = 0.f;
    #pragma unroll
    for (int j = 0; j < 8; j++) { v[j] = expf(v[j] - m); s += v[j]; }
    float inv = 1.f / s;
    lp4[0] = make_float4(v[0] * inv, v[1] * inv, v[2] * inv, v[3] * inv);
    lp4[1] = make_float4(v[4] * inv, v[5] * inv, v[6] * inv, v[7] * inv);
}

extern "C" void kernel_launch(void* const* d_in, const int* in_sizes, int n_in,
                              void* d_out, int out_size, void* d_ws, size_t ws_size,
                              hipStream_t stream) {
    const float* x    = (const float*)d_in[0];
    const int*   ei   = (const int*)d_in[1];
    const float* w1   = (const float*)d_in[2];
    const float* b1   = (const float*)d_in[3];
    const float* w2   = (const float*)d_in[4];
    const float* b2   = (const float*)d_in[5];
    const float* w3   = (const float*)d_in[6];
    const float* b3   = (const float*)d_in[7];
    const float* fc1w = (const float*)d_in[8];
    const float* fc1b = (const float*)d_in[9];
    const float* fc2w = (const float*)d_in[10];
    const float* fc2b = (const float*)d_in[11];
    float* out = (float*)d_out;

    int n = in_sizes[0] / 64;
    int E = in_sizes[1] / 2;
    int NB = (n + 127) >> 7;   // 391 for n=50000; NB <= NB2MAX
    const int* src = ei;
    const int* dst = ei + E;

    char* ws = (char*)d_ws;
    auto carve = [&](size_t bytes) {
        char* p = ws;
        ws += (bytes + 255) & ~((size_t)255);
        return p;
    };
    int*   gcur    = (int*)carve((size_t)NB * 4);
    int*   lcnt3   = (int*)carve(16);                 // contiguous after gcur pad
    int*   ovbuf   = (int*)carve((size_t)NB * OVCAP * 4);
    int*   binsbuf = (int*)carve((size_t)NB * NBLK * CAPC * 4);
    int*   cnts    = (int*)carve((size_t)NBLK * NB * 4);
    unsigned short* csrp_s = (unsigned short*)carve((size_t)3 * n * CAPN * 2); // tier-sorted
    int2*  nd_s    = (int2*)carve((size_t)3 * n * 8);                          // {node,deg}
    int*   csr     = (int*)carve((size_t)NB * CAPB * 4);
    int2*  be      = (int2*)carve((size_t)n * 8);
    __half* buf0   = (__half*)carve((size_t)(n + 1) * 16 * 2);  // +1 zero row
    __half* buf1   = (__half*)carve((size_t)(n + 1) * 16 * 2);
    float* M       = (float*)carve(1024 * 4);
    float* cvec    = (float*)carve(8 * 4);
    float* W31     = (float*)carve(256 * 4);
    float* c31     = (float*)carve(16 * 4);

    // one memset covers gcur (padded to 256) + lcnt3 (next carve slot)
    size_t gpad = ((size_t)NB * 4 + 255) & ~((size_t)255);
    hipMemsetAsync(gcur, 0, gpad + 16, stream);
    binfill_k<<<NBLK + 9, 1024, 0, stream>>>(src, dst, E, n, gcur, ovbuf, binsbuf, cnts,
                                             w1, w3, b3, fc1w, fc1b, fc2w, fc2b,
                                             M, cvec, W31, c31);
    csr2_k<<<NB, 256, 0, stream>>>(binsbuf, cnts, gcur, ovbuf,
                                   csrp_s, nd_s, csr, be, lcnt3, n);

    int FB = (n + 255) / 256;     // field/proj blocks
    int AB = (n + 15) / 16;       // agg blocks (4 nodes/wave, 4 waves/block)
    proj_k<<<FB, 256, 0, stream>>>(x, buf0, buf1, out, w1, b1, w2, b2,
                                   W31, c31, M, cvec, n);

    __half* cur = buf0;
    __half* nxt = buf1;
    // hop 1: agg only (field0 applied in proj)
    hop_k<<<AB, 256, 0, stream>>>(cur, nxt, out, csrp_s, nd_s, be, csr, lcnt3,
                                  w2, b1, b2, M, n, 0);
    { __half* t = cur; cur = nxt; nxt = t; }
    // hops 2..7: field(z_k, M_k) + agg(z_k -> z_{k+1}) in one launch
    for (int k = 1; k <= 6; k++) {
        hop_k<<<FB + AB, 256, 0, stream>>>(cur, nxt, out, csrp_s, nd_s, be, csr,
                                           lcnt3, w2, b1, b2, M + k * 128, n, FB);
        __half* t = cur; cur = nxt; nxt = t;
    }
    // final: field(z7, M7) + softmax
    fieldsoft_k<<<FB, 256, 0, stream>>>(cur, out, w2, b1, b2, M + 7 * 128, n);
}